// Round 4
// baseline (1642.082 us; speedup 1.0000x reference)
//
#include <hip/hip_runtime.h>

// Segment-sum: out[v,:] = sum_{n: X_node[n]==v} H[n,:]
// N=2M rows, D=64, V=100k. fp32.
//
// Round-2 post-mortem: accum with 8-deep MLP (VGPR 52) was byte-identical in
// time to the serialized version (902us vs 895us, both 324 GB/s, FETCH 258MB).
// => random 256B row READS are capped ~570 GB/s effective by a memory-side
// resource, independent of source-level MLP. This round: NO random reads.
// Invert: scatter-WRITE H rows into bucket-sorted order (writes are
// fire-and-forget), then accumulate from a purely SEQUENTIAL stream.
//   A: per-block LDS histogram over C=ceil(V/128) buckets -> [BHIST][C]
//   S1/S2: scans -> exact per-(block,bucket) write offsets (zero global atomics)
//   P1: stream-read H, scatter-write rows to Hs[pos] (256B granules) +
//       nodeloc[pos] (1B, L3-resident 2MB region)
//   P2: per bucket: rows contiguous -> stream Hs, LDS f32-atomic accumulate
//       into 32KB tile, one coalesced 32KB store.
// (Round-3 bench was an infra failure, not a kernel result; this is the same
//  design with BHIST reverted to the proven 512 / VPL=8 scan path.)

constexpr int D     = 64;
constexpr int BHIST = 512;   // blocks for hist/scatter passes (= matrix rows)
constexpr int NPB   = 128;   // nodes per coarse bucket
constexpr int MAXC  = 1024;  // max buckets supported (V <= 131072)

// ---------------- Pass A: per-block coarse histogram ----------------
__global__ __launch_bounds__(256) void bucket_hist_kernel(
    const int* __restrict__ idx, int* __restrict__ matB, int N, int C)
{
    __shared__ int h[MAXC];
    for (int c = threadIdx.x; c < C; c += blockDim.x) h[c] = 0;
    __syncthreads();
    int rpb = (N + BHIST - 1) / BHIST;
    int lo = blockIdx.x * rpb;
    int hi = lo + rpb; if (hi > N) hi = N;
    for (int n = lo + threadIdx.x; n < hi; n += blockDim.x)
        atomicAdd(&h[idx[n] >> 7], 1);           // NPB=128 -> bucket = node>>7
    __syncthreads();
    for (int c = threadIdx.x; c < C; c += blockDim.x)
        matB[blockIdx.x * C + c] = h[c];
}

// ------- Pass S1: per-column (bucket) exclusive scan over blocks -------
// One wave per bucket column. In-place: matB -> per-block exclusive prefix.
__global__ __launch_bounds__(256) void scan_mat_kernel(
    int* __restrict__ mat, int* __restrict__ colsum, int C)
{
    int gw   = (blockIdx.x * blockDim.x + threadIdx.x) >> 6;
    int lane = threadIdx.x & 63;
    if (gw >= C) return;
    int c = gw;
    constexpr int VPL = BHIST / 64;              // 8 matrix rows per lane
    int v[VPL], p[VPL];
    int run = 0;
    #pragma unroll
    for (int j = 0; j < VPL; ++j) {
        v[j] = mat[(lane * VPL + j) * C + c];
        p[j] = run;
        run += v[j];
    }
    int x = run;
    #pragma unroll
    for (int off = 1; off < 64; off <<= 1) {
        int y = __shfl_up(x, off);
        if (lane >= off) x += y;
    }
    int lane_excl = x - run;
    #pragma unroll
    for (int j = 0; j < VPL; ++j)
        mat[(lane * VPL + j) * C + c] = lane_excl + p[j];
    if (lane == 63) colsum[c] = x;
}

// ------- Pass S2: exclusive scan of column totals -> bucket bases -------
__global__ __launch_bounds__(1024) void scan_cols_kernel(
    const int* __restrict__ colsum, int* __restrict__ colbase, int C, int N)
{
    __shared__ int tmp[1024];
    int t = threadIdx.x;
    if (C <= 1024) {
        int x = (t < C) ? colsum[t] : 0;
        tmp[t] = x;
        __syncthreads();
        for (int off = 1; off < 1024; off <<= 1) {
            int y = (t >= off) ? tmp[t - off] : 0;
            __syncthreads();
            tmp[t] += y;
            __syncthreads();
        }
        if (t < C) colbase[t] = tmp[t] - x;
        if (t == 0) colbase[C] = N;
    } else {
        if (t == 0) {
            int run = 0;
            for (int c = 0; c < C; ++c) { colbase[c] = run; run += colsum[c]; }
            colbase[C] = run;
        }
    }
}

// ------- Pass P1: scatter H rows into bucket-sorted Hs -------
// Stream-read H (1KB contiguous per wave-iter), scatter-write 256B rows.
// Quarter-wave (16 lanes) owns one row; float4 per lane.
__global__ __launch_bounds__(256) void scatterH_kernel(
    const float* __restrict__ H, const int* __restrict__ idx,
    const int* __restrict__ matP, const int* __restrict__ colbase,
    float* __restrict__ Hs, unsigned char* __restrict__ nodeloc,
    int N, int C)
{
    __shared__ int cur[MAXC];
    for (int c = threadIdx.x; c < C; c += blockDim.x)
        cur[c] = colbase[c] + matP[blockIdx.x * C + c];
    __syncthreads();
    int rpb = (N + BHIST - 1) / BHIST;
    int lo = blockIdx.x * rpb;
    int hi = lo + rpb; if (hi > N) hi = N;
    if (lo >= hi) return;

    int w = threadIdx.x >> 6, lane = threadIdx.x & 63;
    int q = lane >> 4;               // quarter id (0..3)
    int f = (lane & 15) * 4;         // feature offset (float4)
    int rows   = hi - lo;
    int ntiles = rows >> 6;          // full 64-row tiles

    for (int t = w; t < ntiles; t += 4) {
        int base = lo + (t << 6);
        int node = idx[base + lane];                 // coalesced 256B
        int pos  = atomicAdd(&cur[node >> 7], 1);    // LDS cursor
        nodeloc[pos] = (unsigned char)(node & (NPB - 1));
        #pragma unroll
        for (int s = 0; s < 16; ++s) {
            int rsel = s * 4 + q;                    // row within tile
            int p2   = __shfl(pos, rsel);
            float4 v = *(const float4*)&H[(size_t)(base + rsel) * D + f];
            *(float4*)&Hs[(size_t)p2 * D + f] = v;
        }
    }
    // tail (<64 rows): wave 0
    int tstart = lo + (ntiles << 6);
    int m = hi - tstart;
    if (m > 0 && w == 0) {
        int node = (lane < m) ? idx[tstart + lane] : 0;
        int pos = 0;
        if (lane < m) {
            pos = atomicAdd(&cur[node >> 7], 1);
            nodeloc[pos] = (unsigned char)(node & (NPB - 1));
        }
        for (int s = 0; s < 16; ++s) {
            int rsel = s * 4 + q;
            int p2 = __shfl(pos, rsel);
            if (rsel < m) {
                float4 v = *(const float4*)&H[(size_t)(tstart + rsel) * D + f];
                *(float4*)&Hs[(size_t)p2 * D + f] = v;
            }
        }
    }
}

// ------- Pass P2: one block per bucket; rows contiguous -> pure stream ----
__global__ __launch_bounds__(512) void accum_kernel(
    const float* __restrict__ Hs, const unsigned char* __restrict__ nodeloc,
    const int* __restrict__ colbase, float* __restrict__ out, int V)
{
    __shared__ float acc[NPB * D];               // 32 KB
    int tid = threadIdx.x;
    for (int e = tid; e < NPB * D; e += 512) acc[e] = 0.f;
    __syncthreads();

    int c     = blockIdx.x;
    int start = colbase[c];
    int cnt   = colbase[c + 1] - start;
    int w     = tid >> 6, lane = tid & 63;
    int q     = lane >> 4;
    int f     = (lane & 15) * 4;

    int ngroups = (cnt + 3) >> 2;                // groups of 4 rows
    #pragma unroll 2
    for (int g = w; g < ngroups; g += 8) {
        int rq = (g << 2) + q;                   // this quarter's row
        bool ok = rq < cnt;
        int local = 0;
        float4 v = make_float4(0.f, 0.f, 0.f, 0.f);
        if (ok) {
            local = (int)nodeloc[start + rq];
            v = *(const float4*)&Hs[(size_t)(start + rq) * D + f]; // sequential
        }
        if (ok) {
            atomicAdd(&acc[local * D + f + 0], v.x);
            atomicAdd(&acc[local * D + f + 1], v.y);
            atomicAdd(&acc[local * D + f + 2], v.z);
            atomicAdd(&acc[local * D + f + 3], v.w);
        }
    }
    __syncthreads();

    int vbase = c * NPB;
    int nn = V - vbase; if (nn > NPB) nn = NPB;
    for (int e = tid; e < nn * D; e += 512)
        out[(size_t)vbase * D + e] = acc[e];
}

// ---- fallback (only if ws too small / C too large): direct atomic scatter ----
__global__ __launch_bounds__(256) void scatter_atomic_kernel(
    const float4* __restrict__ H4, const int* __restrict__ idx,
    float* __restrict__ out, int n_rows)
{
    long long t = (long long)blockIdx.x * blockDim.x + threadIdx.x;
    int n = (int)(t >> 4), qq = (int)(t & 15);
    if (n >= n_rows) return;
    int node = idx[n];
    float4 v = H4[(size_t)n * 16 + qq];
    float* o = out + (size_t)node * D + qq * 4;
    atomicAdd(o + 0, v.x); atomicAdd(o + 1, v.y);
    atomicAdd(o + 2, v.z); atomicAdd(o + 3, v.w);
}

static inline size_t align_up(size_t x, size_t a) { return (x + a - 1) & ~(a - 1); }

extern "C" void kernel_launch(void* const* d_in, const int* in_sizes, int n_in,
                              void* d_out, int out_size, void* d_ws, size_t ws_size,
                              hipStream_t stream) {
    const float* H = (const float*)d_in[0];
    const int* idx = (const int*)d_in[1];
    float* out     = (float*)d_out;
    int N = in_sizes[1];
    int V = out_size / D;
    int C = (V + NPB - 1) / NPB;

    // workspace: matB[BHIST*C] | colsum[C] | colbase[C+1] | Hs[N*D] | nodeloc[N]
    size_t off_mat   = 0;
    size_t off_csum  = align_up(off_mat  + (size_t)BHIST * C * 4, 256);
    size_t off_cbase = align_up(off_csum + (size_t)C * 4, 256);
    size_t off_hs    = align_up(off_cbase + ((size_t)C + 1) * 4, 256);
    size_t off_nl    = align_up(off_hs + (size_t)N * D * 4, 256);
    size_t need      = off_nl + (size_t)N;

    if (ws_size < need || C > MAXC) {
        hipMemsetAsync(d_out, 0, (size_t)out_size * sizeof(float), stream);
        long long total = (long long)N * 16;
        scatter_atomic_kernel<<<(int)((total + 255) / 256), 256, 0, stream>>>(
            (const float4*)H, idx, out, N);
        return;
    }

    char* ws = (char*)d_ws;
    int* matB              = (int*)(ws + off_mat);
    int* colsum            = (int*)(ws + off_csum);
    int* colbase           = (int*)(ws + off_cbase);
    float* Hs              = (float*)(ws + off_hs);
    unsigned char* nodeloc = (unsigned char*)(ws + off_nl);

    bucket_hist_kernel<<<BHIST, 256, 0, stream>>>(idx, matB, N, C);
    scan_mat_kernel<<<(C + 3) / 4, 256, 0, stream>>>(matB, colsum, C);
    scan_cols_kernel<<<1, 1024, 0, stream>>>(colsum, colbase, C, N);
    scatterH_kernel<<<BHIST, 256, 0, stream>>>(H, idx, matB, colbase, Hs, nodeloc, N, C);
    accum_kernel<<<C, 512, 0, stream>>>(Hs, nodeloc, colbase, out, V);
}